// Round 4
// baseline (429.675 us; speedup 1.0000x reference)
//
#include <hip/hip_runtime.h>
#include <hip/hip_bf16.h>

#define EPS_F 1e-10f

typedef short s16x8 __attribute__((ext_vector_type(8)));
typedef float f32x4 __attribute__((ext_vector_type(4)));
typedef unsigned short ushort_t;

constexpr int B_ = 8, S_ = 4, C_ = 512, Cq_ = 128, HW_ = 4096;
constexpr long long D_ = (long long)Cq_ * HW_;

__device__ inline float bf_lo(unsigned int u) { return __uint_as_float(u << 16); }
__device__ inline float bf_hi(unsigned int u) { return __uint_as_float(u & 0xffff0000u); }

__device__ inline ushort_t f2bf(float f) {
    __hip_bfloat16 h = __float2bfloat16(f);
    return *reinterpret_cast<ushort_t*>(&h);
}
__device__ inline unsigned int pack_bf2(float a, float b) {
    return (unsigned int)f2bf(a) | ((unsigned int)f2bf(b) << 16);
}
__device__ inline float dot8(uint4 a, uint4 b) {
    return bf_lo(a.x) * bf_lo(b.x) + bf_hi(a.x) * bf_hi(b.x)
         + bf_lo(a.y) * bf_lo(b.y) + bf_hi(a.y) * bf_hi(b.y)
         + bf_lo(a.z) * bf_lo(b.z) + bf_hi(a.z) * bf_hi(b.z)
         + bf_lo(a.w) * bf_lo(b.w) + bf_hi(a.w) * bf_hi(b.w);
}

#define GLOAD16(gp, lp) __builtin_amdgcn_global_load_lds( \
    (const __attribute__((address_space(1))) unsigned int*)(gp), \
    (__attribute__((address_space(3))) unsigned int*)(lp), 16, 0, 0)

#define VMCNT(n) asm volatile("s_waitcnt vmcnt(" #n ")" ::: "memory")
#define LGK0     asm volatile("s_waitcnt lgkmcnt(0)" ::: "memory")
#define MFMA16(a, b, c) __builtin_amdgcn_mfma_f32_16x16x32_bf16(a, b, c, 0, 0, 0)

// ---------------------------------------------------------------------------
// prep3: fp32->bf16 weights, pre-swizzled (chunk slot = c ^ (row&7)) so
// global_load_lds (linear dest) + swizzled ds_read_b128 is conflict-free.
// Also zeroes g4 (8*24*16 floats).
// ---------------------------------------------------------------------------
__global__ __launch_bounds__(256) void prep3(
    const float* __restrict__ wq, const float* __restrict__ wk,
    const float* __restrict__ wv,
    ushort_t* __restrict__ Wqk_pre, ushort_t* __restrict__ Wvb_pre,
    float* __restrict__ g4) {
    int gid = blockIdx.x * 256 + threadIdx.x;
    if (gid < 8 * 24 * 16) g4[gid] = 0.f;
    if (gid < 65536) {                      // Wqk chunks
        int s = gid >> 14;
        int kt = (gid >> 11) & 7;
        int row = (gid >> 3) & 255;
        int slot = gid & 7;
        int col = kt * 64 + ((slot ^ (row & 7)) << 3);
        const float* src = (row < 128)
            ? &wq[((size_t)s * 128 + row) * 512 + col]
            : &wk[((size_t)s * 128 + (row - 128)) * 512 + col];
        float4 f0 = *reinterpret_cast<const float4*>(src);
        float4 f1 = *reinterpret_cast<const float4*>(src + 4);
        uint4 o;
        o.x = pack_bf2(f0.x, f0.y); o.y = pack_bf2(f0.z, f0.w);
        o.z = pack_bf2(f1.x, f1.y); o.w = pack_bf2(f1.z, f1.w);
        *reinterpret_cast<uint4*>(Wqk_pre + (size_t)gid * 8) = o;
    } else {                                 // Wvb chunks
        int c2 = gid - 65536;                // < 131072
        int t = c2 >> 15;
        int ct = (c2 >> 14) & 1;
        int kt = (c2 >> 11) & 7;
        int row = (c2 >> 3) & 255;
        int slot = c2 & 7;
        int col = kt * 64 + ((slot ^ (row & 7)) << 3);
        const float* src = &wv[((size_t)t * 512 + ct * 256 + row) * 512 + col];
        float4 f0 = *reinterpret_cast<const float4*>(src);
        float4 f1 = *reinterpret_cast<const float4*>(src + 4);
        uint4 o;
        o.x = pack_bf2(f0.x, f0.y); o.y = pack_bf2(f0.z, f0.w);
        o.z = pack_bf2(f1.x, f1.y); o.w = pack_bf2(f1.z, f1.w);
        *reinterpret_cast<uint4*>(Wvb_pre + (size_t)c2 * 8) = o;
    }
}

// ---------------------------------------------------------------------------
// Triple-buffered pipeline building blocks (BM=256, BN=64, BK=64, 512 thr
// = 8 waves 4x2, wave tile 64x32, 16 MFMA/wave/step).
// A LDS: [256 rows][slot 8][8 bf16], slot = (k>>3) ^ (row&7)  (linear gload).
// B LDS: [64 p][slot 8][8 bf16],    slot = (k>>3) ^ ((p>>3)&7) ^ (p&7)
//        -> both ds_write_b16 staging AND ds_read_b128 frags are 2-way (free).
// vmcnt ledger (6 vmem/tile: 2 B-reg loads then 4 gload_lds):
//   entry: {B(t+1)[2], A(t+1)[4]} in flight
//   vmcnt(4) -> ds_write B(t+1); issue B(t+2), A(t+2); MFMA(t);
//   vmcnt(6) (drain A(t+1), keep 6); lgkmcnt(0); s_barrier.  Never vmcnt(0)
//   in steady state -- loads span ~1.3 iterations.
// ---------------------------------------------------------------------------
#define STAGE_A(T, bufidx)                                                   \
    { const ushort_t* _tp = ASRC(T);                                         \
      ushort_t* _ld = &AsAll[(bufidx) * 16384];                              \
      _Pragma("unroll")                                                      \
      for (int _i = 0; _i < 4; ++_i)                                         \
          GLOAD16(_tp + ((w4 + _i) << 9) + (lane << 3),                      \
                  _ld + ((w4 + _i) << 9)); }

#define LOAD_B(T, V0, V1)                                                    \
    { const float* _s = BSRC(T);                                             \
      V0 = *reinterpret_cast<const float4*>(_s);                             \
      V1 = *reinterpret_cast<const float4*>(_s + 4); }

#define WRITE_B(bufidx, V0, V1)                                              \
    { float _vv[8] = {V0.x, V0.y, V0.z, V0.w, V1.x, V1.y, V1.z, V1.w};       \
      ushort_t* _bd = &BsAll[(bufidx) * 4096 + bw_row0];                     \
      _Pragma("unroll")                                                      \
      for (int _j = 0; _j < 8; ++_j)                                         \
          _bd[_j * 64 + ((bw_sb ^ _j) << 3)] = f2bf(_vv[_j]); }

#define COMPUTE(bufidx)                                                      \
    { const int _ab = (bufidx) * 16384, _bb = (bufidx) * 4096;               \
      _Pragma("unroll")                                                      \
      for (int h = 0; h < 2; ++h) {                                          \
          s16x8 af0 = *reinterpret_cast<const s16x8*>(                       \
              &AsAll[_ab + (arow + 0 * 16 + li) * 64 + a_sl[h]]);            \
          s16x8 af1 = *reinterpret_cast<const s16x8*>(                       \
              &AsAll[_ab + (arow + 1 * 16 + li) * 64 + a_sl[h]]);            \
          s16x8 af2 = *reinterpret_cast<const s16x8*>(                       \
              &AsAll[_ab + (arow + 2 * 16 + li) * 64 + a_sl[h]]);            \
          s16x8 af3 = *reinterpret_cast<const s16x8*>(                       \
              &AsAll[_ab + (arow + 3 * 16 + li) * 64 + a_sl[h]]);            \
          s16x8 bf0 = *reinterpret_cast<const s16x8*>(                       \
              &BsAll[_bb + bp0 * 64 + b_sl0[h]]);                            \
          s16x8 bf1 = *reinterpret_cast<const s16x8*>(                       \
              &BsAll[_bb + bp1 * 64 + b_sl1[h]]);                            \
          __builtin_amdgcn_s_setprio(1);                                     \
          acc[0][0] = MFMA16(af0, bf0, acc[0][0]);                           \
          acc[0][1] = MFMA16(af0, bf1, acc[0][1]);                           \
          acc[1][0] = MFMA16(af1, bf0, acc[1][0]);                           \
          acc[1][1] = MFMA16(af1, bf1, acc[1][1]);                           \
          acc[2][0] = MFMA16(af2, bf0, acc[2][0]);                           \
          acc[2][1] = MFMA16(af2, bf1, acc[2][1]);                           \
          acc[3][0] = MFMA16(af3, bf0, acc[3][0]);                           \
          acc[3][1] = MFMA16(af3, bf1, acc[3][1]);                           \
          __builtin_amdgcn_s_setprio(0);                                     \
      } }

#define PIPE_PROLOGUE()                                                      \
    LOAD_B(0, nbE0, nbE1);                                                   \
    STAGE_A(0, 0);                                                           \
    LOAD_B(1, nbO0, nbO1);                                                   \
    STAGE_A(1, 1);                                                           \
    VMCNT(10);                                                               \
    WRITE_B(0, nbE0, nbE1);                                                  \
    VMCNT(6);                                                                \
    LGK0;                                                                    \
    __builtin_amdgcn_s_barrier();

#define PIPE_ITER(T, WB0, WB1, LB0, LB1)                                     \
    {                                                                        \
        const int _t = (T);                                                  \
        if (_t + 1 < NT) { VMCNT(4); WRITE_B(oN, WB0, WB1); }                \
        if (_t + 2 < NT) { LOAD_B(_t + 2, LB0, LB1); STAGE_A(_t + 2, oNN); } \
        COMPUTE(oC);                                                         \
        ITER_EXTRA(_t);                                                      \
        if (_t + 1 < NT) {                                                   \
            if (_t + 2 < NT) { VMCNT(6); } else { VMCNT(0); }                \
            LGK0;                                                            \
            __builtin_amdgcn_s_barrier();                                    \
        }                                                                    \
        int _r = oC; oC = oN; oN = oNN; oNN = _r;                            \
    }

#define PIPE_COMMON_DECLS()                                                  \
    const int tid = threadIdx.x;                                             \
    const int w = tid >> 6, lane = tid & 63;                                 \
    const int w4 = w * 4;                                                    \
    const int wr = w >> 1, wc = w & 1;                                       \
    const int li = lane & 15, lk = lane >> 4;                                \
    const int arow = wr * 64;                                                \
    const int bp0 = wc * 32 + li, bp1 = wc * 32 + 16 + li;                   \
    int a_sl[2], b_sl0[2], b_sl1[2];                                         \
    _Pragma("unroll")                                                        \
    for (int h = 0; h < 2; ++h) {                                            \
        a_sl[h] = (((h * 4 + lk) ^ (li & 7)) << 3);                          \
        b_sl0[h] = (((h * 4 + lk) ^ ((bp0 >> 3) & 7) ^ (bp0 & 7)) << 3);     \
        b_sl1[h] = (((h * 4 + lk) ^ ((bp1 >> 3) & 7) ^ (bp1 & 7)) << 3);     \
    }                                                                        \
    const int sk = tid >> 3, sp = (tid & 7) * 8;                             \
    const int bw_row0 = sp * 64 + ((tid >> 3) & 7);                          \
    const int bw_sb = (tid >> 6) ^ (tid & 7);                                \
    int oC = 0, oN = 1, oNN = 2;                                             \
    float4 nbE0, nbE1, nbO0, nbO1;                                           \
    f32x4 acc[4][2];                                                         \
    _Pragma("unroll")                                                        \
    for (int mf = 0; mf < 4; ++mf)                                           \
        _Pragma("unroll")                                                    \
        for (int nf = 0; nf < 2; ++nf) acc[mf][nf] = 0.f;

// ---------------------------------------------------------------------------
// qk4: [Wq;Wk](256x512) @ X[b,t](512x4096) + bias -> Qb, Kb (bf16)
// ---------------------------------------------------------------------------
#define ASRC(T) (Wqk_pre + ((size_t)(s * 8 + (T)) << 14))
#define BSRC(T) (x + (size_t)bt * C_ * HW_ + (size_t)((T) * 64 + sk) * HW_ + p0 + sp)
#define ITER_EXTRA(T)

__global__ __launch_bounds__(512) void qk4(
    const ushort_t* __restrict__ Wqk_pre, const float* __restrict__ x,
    const float* __restrict__ bq, const float* __restrict__ bk,
    ushort_t* __restrict__ Qb, ushort_t* __restrict__ Kb) {

    constexpr int NT = 8;
    // XCD-aware swizzle (2048 blocks, 8 XCDs, 256/XCD): contiguous ids/XCD
    const int id = ((blockIdx.x & 7) << 8) | (blockIdx.x >> 3);
    const int bt = id >> 6;
    const int s = bt & 3;
    const int p0 = (id & 63) * 64;

    __shared__ __align__(16) ushort_t AsAll[3 * 16384];
    __shared__ __align__(16) ushort_t BsAll[3 * 4096];

    PIPE_COMMON_DECLS();
    PIPE_PROLOGUE();

    for (int t0 = 0; t0 < NT; t0 += 2) {
        PIPE_ITER(t0,     nbO0, nbO1, nbE0, nbE1);
        PIPE_ITER(t0 + 1, nbE0, nbE1, nbO0, nbO1);
    }

    // epilogue: +bias, split Q/K (wave-uniform: wr<2 -> Q)
#pragma unroll
    for (int mf = 0; mf < 4; ++mf) {
#pragma unroll
        for (int r = 0; r < 4; ++r) {
            int m = wr * 64 + mf * 16 + lk * 4 + r;
            float bias = (m < 128) ? bq[s * 128 + m] : bk[s * 128 + (m - 128)];
#pragma unroll
            for (int nf = 0; nf < 2; ++nf) {
                int p = p0 + wc * 32 + nf * 16 + li;
                float vv = acc[mf][nf][r] + bias;
                if (m < 128)
                    Qb[(size_t)bt * D_ + (size_t)m * HW_ + p] = f2bf(vv);
                else
                    Kb[(size_t)bt * D_ + (size_t)(m - 128) * HW_ + p] = f2bf(vv);
            }
        }
    }
}
#undef ASRC
#undef BSRC
#undef ITER_EXTRA

// ---------------------------------------------------------------------------
// vblend4: fused V-GEMM + attention blend + bias + gamma + residual.
// 32 pipelined tiles (4 t x 8 kt); per-s masters in registers; att staged in
// LDS (no global loads inside the vmcnt-counted loop).
// ---------------------------------------------------------------------------
#define ASRC(T) (Wvb_pre + (((size_t)(((T) >> 3) * 2 + ct) * 8 + ((T) & 7)) << 14))
#define BSRC(T) (x + ((size_t)(b * 4 + ((T) >> 3)) * 512 + ((T) & 7) * 64 + sk) * HW_ + p0 + sp)
#define ITER_EXTRA(T)                                                        \
    if (((T) & 7) == 7) {                                                    \
        const int _t2 = (T) >> 3;                                            \
        float _wv[4];                                                        \
        _Pragma("unroll")                                                    \
        for (int _so = 0; _so < 4; ++_so) _wv[_so] = attL[_so * 4 + _t2];    \
        _Pragma("unroll")                                                    \
        for (int _so = 0; _so < 4; ++_so)                                    \
            _Pragma("unroll")                                                \
            for (int _mf = 0; _mf < 4; ++_mf)                                \
                _Pragma("unroll")                                            \
                for (int _nf = 0; _nf < 2; ++_nf)                            \
                    mst[_so][_mf][_nf] += _wv[_so] * acc[_mf][_nf];          \
        _Pragma("unroll")                                                    \
        for (int _mf = 0; _mf < 4; ++_mf)                                    \
            _Pragma("unroll")                                                \
            for (int _nf = 0; _nf < 2; ++_nf) acc[_mf][_nf] = 0.f;           \
    }

__global__ __launch_bounds__(512) void vblend4(
    const ushort_t* __restrict__ Wvb_pre, const float* __restrict__ x,
    const float* __restrict__ bv, const float* __restrict__ att,
    const float* __restrict__ gamma, float* __restrict__ out) {

    constexpr int NT = 32;
    // XCD swizzle (1024 blocks, 128/XCD): one XCD works one (b, ct) panel
    const int id = ((blockIdx.x & 7) << 7) | (blockIdx.x >> 3);
    const int b = id >> 7;
    const int ct = (id >> 6) & 1;
    const int p0 = (id & 63) * 64;

    __shared__ __align__(16) ushort_t AsAll[3 * 16384];
    __shared__ __align__(16) ushort_t BsAll[3 * 4096];
    __shared__ float attL[16];

    // stage att -> LDS; full drain so the vmcnt ledger starts clean
    if (threadIdx.x < 16) attL[threadIdx.x] = att[b * 16 + threadIdx.x];
    __syncthreads();

    PIPE_COMMON_DECLS();

    f32x4 mst[4][4][2];
#pragma unroll
    for (int so = 0; so < 4; ++so)
#pragma unroll
        for (int mf = 0; mf < 4; ++mf)
#pragma unroll
            for (int nf = 0; nf < 2; ++nf) mst[so][mf][nf] = 0.f;

    PIPE_PROLOGUE();

    for (int t0 = 0; t0 < NT; t0 += 2) {
        PIPE_ITER(t0,     nbO0, nbO1, nbE0, nbE1);
        PIPE_ITER(t0 + 1, nbE0, nbE1, nbO0, nbO1);
    }

    // epilogue: out = gm*(mst + sum_t att*bv) + x
    const float gm = gamma[0];
    const int c0 = ct * 256;
#pragma unroll
    for (int mf = 0; mf < 4; ++mf) {
#pragma unroll
        for (int r = 0; r < 4; ++r) {
            int c = c0 + wr * 64 + mf * 16 + lk * 4 + r;
            float bvv[4];
#pragma unroll
            for (int t = 0; t < 4; ++t) bvv[t] = bv[(size_t)t * 512 + c];
#pragma unroll
            for (int so = 0; so < 4; ++so) {
                float bsum = attL[so * 4 + 0] * bvv[0] + attL[so * 4 + 1] * bvv[1]
                           + attL[so * 4 + 2] * bvv[2] + attL[so * 4 + 3] * bvv[3];
#pragma unroll
                for (int nf = 0; nf < 2; ++nf) {
                    int p = p0 + wc * 32 + nf * 16 + li;
                    size_t off = ((size_t)(b * 4 + so) * C_ + c) * HW_ + p;
                    out[off] = gm * (mst[so][mf][nf][r] + bsum) + x[off];
                }
            }
        }
    }
}
#undef ASRC
#undef BSRC
#undef ITER_EXTRA

// ---------------------------------------------------------------------------
// gram5: all 24 reductions (16 qk + 4 qq + 4 kk) per (b, D/16-slice) in one
// block -- Q/K read ONCE (64 MB total vs 384 MB). Deterministic 2-stage.
// ---------------------------------------------------------------------------
__global__ __launch_bounds__(256) void gram5(
    const ushort_t* __restrict__ Q, const ushort_t* __restrict__ K,
    float* __restrict__ g4) {

    const int ch = blockIdx.x;       // 0..15
    const int b  = blockIdx.y;       // 0..7
    const size_t base = (size_t)ch * (D_ / 16);

    const uint4* qv[4];
    const uint4* kv[4];
#pragma unroll
    for (int s = 0; s < 4; ++s) {
        qv[s] = reinterpret_cast<const uint4*>(Q + (size_t)(b * 4 + s) * D_ + base);
        kv[s] = reinterpret_cast<const uint4*>(K + (size_t)(b * 4 + s) * D_ + base);
    }

    float accr[24];
#pragma unroll
    for (int e = 0; e < 24; ++e) accr[e] = 0.f;

    const int n8 = (int)(D_ / 16 / 8);   // 4096 uint4 per vector slice
    for (int i = threadIdx.x; i < n8; i += 256) {
        uint4 qa[4], ka[4];
#pragma unroll
        for (int s = 0; s < 4; ++s) { qa[s] = qv[s][i]; ka[s] = kv[s][i]; }
#pragma unroll
        for (int s = 0; s < 4; ++s) {
#pragma unroll
            for (int u = 0; u < 4; ++u) accr[s * 4 + u] += dot8(qa[s], ka[u]);
            accr[16 + s] += dot8(qa[s], qa[s]);
            accr[20 + s] += dot8(ka[s], ka[s]);
        }
    }

    __shared__ float red[4][24];
    const int lane = threadIdx.x & 63, wid = threadIdx.x >> 6;
#pragma unroll
    for (int e = 0; e < 24; ++e) {
        float v = accr[e];
#pragma unroll
        for (int o = 32; o > 0; o >>= 1) v += __shfl_down(v, o);
        if (lane == 0) red[wid][e] = v;
    }
    __syncthreads();
    if (threadIdx.x < 24) {
        float t = red[0][threadIdx.x] + red[1][threadIdx.x]
                + red[2][threadIdx.x] + red[3][threadIdx.x];
        g4[((size_t)b * 24 + threadIdx.x) * 16 + ch] = t;
    }
}

// ---------------------------------------------------------------------------
// att_k5: sum 16 chunks per entry, cosine energy + softmax -> att (B,S,S)
// ---------------------------------------------------------------------------
__global__ void att_k5(const float* __restrict__ g4, float* __restrict__ att) {
    const int b = threadIdx.x;
    if (b >= B_) return;
    float e_[24];
#pragma unroll
    for (int e = 0; e < 24; ++e) {
        const float* p = g4 + ((size_t)b * 24 + e) * 16;
        float t = 0.f;
#pragma unroll
        for (int ch = 0; ch < 16; ++ch) t += p[ch];
        e_[e] = t;
    }
    float nq[4], nk[4];
#pragma unroll
    for (int s = 0; s < 4; ++s) {
        nq[s] = sqrtf(e_[16 + s]) + EPS_F;
        nk[s] = sqrtf(e_[20 + s]) + EPS_F;
    }
#pragma unroll
    for (int s = 0; s < 4; ++s) {
        float e[4], m = -1e30f;
#pragma unroll
        for (int t = 0; t < 4; ++t) {
            e[t] = e_[s * 4 + t] / (nq[s] * nk[t]);
            m = fmaxf(m, e[t]);
        }
        float sum = 0.f;
#pragma unroll
        for (int t = 0; t < 4; ++t) { e[t] = expf(e[t] - m); sum += e[t]; }
#pragma unroll
        for (int t = 0; t < 4; ++t) att[(size_t)(b * 4 + s) * 4 + t] = e[t] / sum;
    }
}

extern "C" void kernel_launch(void* const* d_in, const int* in_sizes, int n_in,
                              void* d_out, int out_size, void* d_ws, size_t ws_size,
                              hipStream_t stream) {
    const float* x     = (const float*)d_in[0];
    const float* wq    = (const float*)d_in[1];
    const float* bq    = (const float*)d_in[2];
    const float* wk    = (const float*)d_in[3];
    const float* bk    = (const float*)d_in[4];
    const float* wv    = (const float*)d_in[5];
    const float* bv    = (const float*)d_in[6];
    const float* gamma = (const float*)d_in[7];
    float* out = (float*)d_out;

    char* ws = (char*)d_ws;
    const size_t qk_elems = (size_t)B_ * S_ * Cq_ * HW_;   // 16,777,216
    ushort_t* Qb      = (ushort_t*)ws;                     // 33.55 MB
    ushort_t* Kb      = Qb + qk_elems;                     // 33.55 MB
    ushort_t* Wqk_pre = Kb + qk_elems;                     // 1.05 MB
    ushort_t* Wvb_pre = Wqk_pre + (size_t)4 * 8 * 256 * 64;    // 2.10 MB
    float*    g4      = (float*)(Wvb_pre + (size_t)4 * 2 * 8 * 256 * 64);
    float*    att     = g4 + 8 * 24 * 16;

    prep3<<<768, 256, 0, stream>>>(wq, wk, wv, Wqk_pre, Wvb_pre, g4);
    qk4<<<2048, 512, 0, stream>>>(Wqk_pre, x, bq, bk, Qb, Kb);
    gram5<<<dim3(16, 8), 256, 0, stream>>>(Qb, Kb, g4);
    att_k5<<<1, 64, 0, stream>>>(g4, att);
    vblend4<<<1024, 512, 0, stream>>>(Wvb_pre, x, bv, att, gamma, out);
}